// Round 5
// baseline (626.769 us; speedup 1.0000x reference)
//
#include <hip/hip_runtime.h>
#include <hip/hip_fp16.h>
#include <math.h>

#define H 512
#define W 512
#define S (H*W)
#define BS 16
#define CH 3
#define NP (BS*CH)

#define T5    5                        // steps per kernel (2 kernels = 10)
#define NW    8                        // waves per block
#define RPW   4                        // rows per wave (in registers)
#define R     (NW*RPW)                 // 32 extended rows per block
#define STRIP (R - 2*T5)               // 22 rows correct after 5 steps
#define NBX   ((H + STRIP - 1)/STRIP)  // 24
#define NTHR  (NW*64)                  // 512

typedef unsigned int   uint_t;
typedef unsigned short ush;

struct F8 { float f[8]; };

__device__ __forceinline__ F8 unpk(uint4 r) {
  F8 o;
  float2 a = __half22float2(*(__half2*)&r.x); o.f[0]=a.x; o.f[1]=a.y;
  float2 b = __half22float2(*(__half2*)&r.y); o.f[2]=b.x; o.f[3]=b.y;
  float2 c = __half22float2(*(__half2*)&r.z); o.f[4]=c.x; o.f[5]=c.y;
  float2 d = __half22float2(*(__half2*)&r.w); o.f[6]=d.x; o.f[7]=d.y;
  return o;
}
__device__ __forceinline__ uint_t pk2(float a, float b) {
  __half2 h = __floats2half2_rn(a, b); return *(uint_t*)&h;
}
__device__ __forceinline__ uint4 pk8(const float* f) {
  return make_uint4(pk2(f[0],f[1]), pk2(f[2],f[3]), pk2(f[4],f[5]), pk2(f[6],f[7]));
}
__device__ __forceinline__ uint4 pkf8(float4 a, float4 b) {
  return make_uint4(pk2(a.x,a.y), pk2(a.z,a.w), pk2(b.x,b.y), pk2(b.z,b.w));
}
__device__ __forceinline__ float hi_h(uint_t u){ return __half22float2(*(__half2*)&u).y; }
__device__ __forceinline__ float lo_h(uint_t u){ return __half22float2(*(__half2*)&u).x; }

// tau = 1/(5 + 4 cos(pi(2k-1)/20)), Lebedev order k = 1,10,2,9,3,8,4,7,5,6
__device__ const float TAUS[10] = {
  0.11172248f, 0.95306479f, 0.11676753f, 0.69639146f, 0.12773959f,
  0.46049561f, 0.14671469f, 0.31406661f, 0.17775436f, 0.22860982f };

// 5 Chebyshev steps fused per kernel; two kernels make the 10-step solve.
// x lives packed-fp16 in REGISTERS (4 rows/wave); LDS holds only a 4-deep
// boundary-row exchange (exactly 64 KiB). Geometry is chosen FOR the VGPR
// allocator heuristic (it targets LDS-implied occupancy, rounds 1/2/4
// evidence): 512-thr block + 64 KiB LDS -> 2 blocks/CU = 4 waves/EU ->
// 128-VGPR budget, which fits the ~72 persistent + ~45 working regs with
// no scratch spill (rounds 2/4 at 64 VGPRs spilled >1 GB).
template <int STAGE>   // 0: x0 = fp16(b), out fp16 -> XWS ; 1: x0 = XWS, out fp32 -> OUT
__attribute__((amdgpu_waves_per_eu(4, 4)))
__global__ void __launch_bounds__(NTHR)
cheb5(const float* __restrict__ Bsrc, const float* __restrict__ WCs,
      const float* __restrict__ WRs, ush* __restrict__ XWS,
      float* __restrict__ OUT)
{
  __shared__ __align__(16) ush ex[4][NW][2][W];   // 64 KiB exchange (quad buf)

  const int j  = blockIdx.y;                    // plane 0..47
  const int bb = j / CH;                        // batch
  const int y0 = (int)blockIdx.x * STRIP;       // first interior row
  const int ys = y0 - T5;                       // first extended row
  const int tid = (int)threadIdx.x;
  const int wv = tid >> 6, lane = tid & 63;
  const uint4 zz = make_uint4(0,0,0,0);

  const float* bp = Bsrc + (size_t)j  * S;
  const float* wc = WCs  + (size_t)bb * (size_t)(H-1) * W;
  const float* wr = WRs  + (size_t)bb * (size_t)H * (W-1);
  const ush*   xp = XWS  + (size_t)j  * S;

  // ---- init: load inputs once, pack to fp16 regs ----
  const int rb = wv * RPW;                      // wave's first row (tile-rel)
  uint4 xpk[RPW], bpk[RPW], wca[RPW+1], wrp[RPW];
  float wlmr[RPW];
#pragma unroll
  for (int i = 0; i < RPW; ++i) {
    const int y = ys + rb + i;
    uint4 bv = zz, wrv = zz;
    if ((unsigned)y < H) {
      const float* p = bp + (size_t)y*W + lane*8;
      bv = pkf8(*(const float4*)p, *(const float4*)(p + 4));
      // wr rows have stride 511 floats (unaligned) -> scalar loads; col 511=0
      const float* q = wr + (size_t)y*(W-1) + lane*8;
      const float a0=q[0],a1=q[1],a2=q[2],a3=q[3],a4=q[4],a5=q[5],a6=q[6];
      const float a7 = (lane < 63) ? q[7] : 0.f;
      wrv = make_uint4(pk2(a0,a1), pk2(a2,a3), pk2(a4,a5), pk2(a6,a7));
    }
    bpk[i] = bv; wrp[i] = wrv;
    if (STAGE == 0) {
      xpk[i] = bv;                              // x0 = fp16(b)
    } else {
      xpk[i] = ((unsigned)y < H) ? *(const uint4*)(xp + (size_t)y*W + lane*8)
                                 : zz;          // x0 = stage-1 result
    }
    // left-neighbor row-weight for px 0 of this lane: step-invariant, hoisted
    const uint_t uw = (uint_t)__shfl_up((int)wrv.w, 1);
    wlmr[i] = lane ? hi_h(uw) : 0.f;
  }
#pragma unroll
  for (int i = 0; i <= RPW; ++i) {              // wc rows y(0)-1 .. y(RPW-1)
    const int y = ys + rb - 1 + i;
    uint4 wv4 = zz;
    if ((unsigned)y < (H-1)) {
      const float* p = wc + (size_t)y*W + lane*8;
      wv4 = pkf8(*(const float4*)p, *(const float4*)(p + 4));
    }
    wca[i] = wv4;
  }

  // ---- 5 steps; one barrier per step (quad-buffered exchange) ----
#pragma unroll 1
  for (int t = 0; t < T5; ++t) {
    const float tau = TAUS[STAGE*T5 + t];
    const int buf = t & 3;
    *(uint4*)&ex[buf][wv][0][lane*8] = xpk[0];
    *(uint4*)&ex[buf][wv][1][lane*8] = xpk[RPW-1];
    __syncthreads();
    const uint4 xup = wv          ? *(const uint4*)&ex[buf][wv-1][1][lane*8] : zz;
    const uint4 xdn = (wv < NW-1) ? *(const uint4*)&ex[buf][wv+1][0][lane*8] : zz;
    const bool last = (t == T5-1);

    uint4 xprev = xup;                          // old x of row i-1
#pragma unroll
    for (int i = 0; i < RPW; ++i) {
      const uint4 xc_pk = xpk[i];
      const uint4 xd_pk = (i < RPW-1) ? xpk[i+1] : xdn;
      const uint_t ux  = (uint_t)__shfl_up((int)xc_pk.w, 1);
      const float xl0  = lane ? hi_h(ux) : 0.f;
      const uint_t dxp = (uint_t)__shfl_down((int)xc_pk.x, 1);
      const float xr7  = (lane < 63) ? lo_h(dxp) : 0.f;
      const F8 xc = unpk(xc_pk), xu = unpk(xprev), xd = unpk(xd_pk);
      const F8 wu = unpk(wca[i]), wd = unpk(wca[i+1]);
      const F8 w  = unpk(wrp[i]), b  = unpk(bpk[i]);
      float o[8];
#pragma unroll
      for (int p = 0; p < 8; ++p) {
        const float wl  = p ? w.f[p-1] : wlmr[i];
        const float wrv = w.f[p];
        const float xl  = p ? xc.f[p-1] : xl0;
        const float xr  = (p < 7) ? xc.f[p+1] : xr7;
        const float kv  = 1.f + wu.f[p] + wd.f[p] + wl + wrv;
        const float av  = kv * xc.f[p] - wu.f[p]*xu.f[p] - wd.f[p]*xd.f[p]
                          - wl*xl - wrv*xr;
        o[p] = xc.f[p] + tau * (b.f[p] - av);
      }
      xprev = xc_pk;                            // old center -> next row's up
      if (!last) {
        xpk[i] = pk8(o);
      } else {
        const int y = ys + rb + i;
        if (y >= y0 && y < y0 + STRIP && y < H) {
          if (STAGE == 0) {
            *(uint4*)(XWS + (size_t)j*S + (size_t)y*W + lane*8) = pk8(o);
          } else {
            float* dst = OUT + (size_t)j*S + (size_t)y*W + lane*8;
            *(float4*)dst       = make_float4(o[0],o[1],o[2],o[3]);
            *(float4*)(dst + 4) = make_float4(o[4],o[5],o[6],o[7]);
          }
        }
      }
    }
  }
}

extern "C" void kernel_launch(void* const* d_in, const int* in_sizes, int n_in,
                              void* d_out, int out_size, void* d_ws, size_t ws_size,
                              hipStream_t stream) {
  (void)in_sizes; (void)n_in; (void)out_size; (void)ws_size;
  const float* Bp = (const float*)d_in[0];
  const float* WC = (const float*)d_in[1];
  const float* WR = (const float*)d_in[2];
  ush* X5 = (ush*)d_ws;                         // 25.2 MB fp16 intermediate
  dim3 grid(NBX, NP), block(NTHR);
  cheb5<0><<<grid, block, 0, stream>>>(Bp, WC, WR, X5, nullptr);
  cheb5<1><<<grid, block, 0, stream>>>(Bp, WC, WR, X5, (float*)d_out);
}

// Round 7
// 284.740 us; speedup vs baseline: 2.2012x; 2.2012x over previous
//
#include <hip/hip_runtime.h>
#include <hip/hip_fp16.h>
#include <math.h>

#define H 512
#define W 512
#define S (H*W)
#define BS 16
#define CH 3
#define NP (BS*CH)

#define T5    5                        // steps per kernel (2 kernels = 10)
#define NW    8                        // waves per block
#define RPW   4                        // rows per wave (x in registers)
#define R     (NW*RPW)                 // 32 extended rows per block
#define STRIP (R - 2*T5)               // 22 rows correct after 5 steps
#define NBX   ((H + STRIP - 1)/STRIP)  // 24
#define NTHR  (NW*64)                  // 512

typedef unsigned int   uint_t;
typedef unsigned short ush;

struct F8 { float f[8]; };

__device__ __forceinline__ F8 unpk(uint4 r) {
  F8 o;
  float2 a = __half22float2(*(__half2*)&r.x); o.f[0]=a.x; o.f[1]=a.y;
  float2 b = __half22float2(*(__half2*)&r.y); o.f[2]=b.x; o.f[3]=b.y;
  float2 c = __half22float2(*(__half2*)&r.z); o.f[4]=c.x; o.f[5]=c.y;
  float2 d = __half22float2(*(__half2*)&r.w); o.f[6]=d.x; o.f[7]=d.y;
  return o;
}
__device__ __forceinline__ uint_t pk2(float a, float b) {
  __half2 h = __floats2half2_rn(a, b); return *(uint_t*)&h;
}
__device__ __forceinline__ uint4 pk8(const float* f) {
  return make_uint4(pk2(f[0],f[1]), pk2(f[2],f[3]), pk2(f[4],f[5]), pk2(f[6],f[7]));
}
__device__ __forceinline__ uint4 pkf8(float4 a, float4 b) {
  return make_uint4(pk2(a.x,a.y), pk2(a.z,a.w), pk2(b.x,b.y), pk2(b.z,b.w));
}
__device__ __forceinline__ float hi_h(uint_t u){ return __half22float2(*(__half2*)&u).y; }
__device__ __forceinline__ float lo_h(uint_t u){ return __half22float2(*(__half2*)&u).x; }

// tau = 1/(5 + 4 cos(pi(2k-1)/20)), Lebedev order k = 1,10,2,9,3,8,4,7,5,6
__device__ const float TAUS[10] = {
  0.11172248f, 0.95306479f, 0.11676753f, 0.69639146f, 0.12773959f,
  0.46049561f, 0.14671469f, 0.31406661f, 0.17775436f, 0.22860982f };

// 5 Chebyshev steps per kernel; two launches make the 10-step solve.
// x: packed fp16 in REGISTERS (4 rows/wave, 16 VGPRs). b/wc/wr: fp16 in LDS
// (step-invariant, staged once; ~6 B/px-step of LDS reads ~= 7 us total).
// LDS = 129 KiB -> 1 block/CU; with the ONLY attribute combo that has ever
// yielded a 128-VGPR budget here (non-template, __launch_bounds__(512,2),
// LDS > 80 KiB; rounds 2/4/5 with other combos all got 64 VGPRs and spilled
// >0.5 GB). Peak live estimate ~100 regs -> no spill at 128.
__global__ void __launch_bounds__(NTHR, 2)
cheb5(const float* __restrict__ Bsrc, const float* __restrict__ WCs,
      const float* __restrict__ WRs, ush* __restrict__ XWS,
      float* __restrict__ OUT, int stage)
{
  __shared__ __align__(16) ush bl [R    ][W];     // 32 KiB  b rows ys..ys+31
  __shared__ __align__(16) ush wcl[R + 1][W];     // 33 KiB  wc rows ys-1..ys+31
  __shared__ __align__(16) ush wrl[R    ][W];     // 32 KiB  wr rows (col 511 = 0)
  __shared__ __align__(16) ush ex[2][NW][2][W];   // 32 KiB  boundary exchange

  const int j  = blockIdx.y;                    // plane 0..47
  const int bb = j / CH;                        // batch
  const int y0 = (int)blockIdx.x * STRIP;       // first interior row
  const int ys = y0 - T5;                       // first extended row
  const int tid = (int)threadIdx.x;
  const int wv = tid >> 6, lane = tid & 63;
  const uint4 zz = make_uint4(0,0,0,0);

  const float* bp = Bsrc + (size_t)j  * S;
  const float* wc = WCs  + (size_t)bb * (size_t)(H-1) * W;
  const float* wr = WRs  + (size_t)bb * (size_t)H * (W-1);
  const ush*   xp = XWS  + (size_t)j  * S;

  // ---- stage inputs into LDS (fp32 -> packed fp16), cooperative ----
  for (int r = wv; r < R; r += NW) {            // b
    const int y = ys + r;
    uint4 v = zz;
    if ((unsigned)y < H) {
      const float* p = bp + (size_t)y*W + lane*8;
      v = pkf8(*(const float4*)p, *(const float4*)(p + 4));
    }
    *(uint4*)&bl[r][lane*8] = v;
  }
  for (int r = wv; r <= R; r += NW) {           // wc (R+1 rows)
    const int y = ys + r - 1;
    uint4 v = zz;
    if ((unsigned)y < (H-1)) {
      const float* p = wc + (size_t)y*W + lane*8;
      v = pkf8(*(const float4*)p, *(const float4*)(p + 4));
    }
    *(uint4*)&wcl[r][lane*8] = v;
  }
  for (int r = wv; r < R; r += NW) {            // wr (stride-511 src, pad col 511)
    const int y = ys + r;
    uint4 v = zz;
    if ((unsigned)y < H) {
      const float* q = wr + (size_t)y*(W-1) + lane*8;
      const float a0=q[0],a1=q[1],a2=q[2],a3=q[3],a4=q[4],a5=q[5],a6=q[6];
      const float a7 = (lane < 63) ? q[7] : 0.f;
      v = make_uint4(pk2(a0,a1), pk2(a2,a3), pk2(a4,a5), pk2(a6,a7));
    }
    *(uint4*)&wrl[r][lane*8] = v;
  }
  __syncthreads();

  // ---- per-wave x state (packed fp16 regs) + left-edge row weights ----
  const int rb = wv * RPW;
  uint4 xpk[RPW];
  float wlmr[RPW];
#pragma unroll
  for (int i = 0; i < RPW; ++i) {
    const int y = ys + rb + i;
    if (stage == 0) {
      xpk[i] = *(const uint4*)&bl[rb + i][lane*8];          // x0 = fp16(b)
    } else {
      xpk[i] = ((unsigned)y < H) ? *(const uint4*)(xp + (size_t)y*W + lane*8)
                                 : zz;                      // x0 = stage-0 out
    }
    // left row-weight of this lane's first px (wr[y][lane*8-1]); 2B-aligned LDS read
    wlmr[i] = lane ? __half2float(*(const __half*)&wrl[rb + i][lane*8 - 1]) : 0.f;
  }

  // ---- 5 steps; one barrier per step (2-deep exchange is race-free:
  // reads of buf k happen before the next barrier, writes of buf k
  // recur only two barriers later) ----
#pragma unroll 1
  for (int t = 0; t < T5; ++t) {
    const float tau = TAUS[stage*T5 + t];
    const int buf = t & 1;
    *(uint4*)&ex[buf][wv][0][lane*8] = xpk[0];
    *(uint4*)&ex[buf][wv][1][lane*8] = xpk[RPW-1];
    __syncthreads();
    const uint4 xup = wv          ? *(const uint4*)&ex[buf][wv-1][1][lane*8] : zz;
    const uint4 xdn = (wv < NW-1) ? *(const uint4*)&ex[buf][wv+1][0][lane*8] : zz;
    const bool last = (t == T5-1);

    F8 xu = unpk(xup);                          // rolling: up, center unpacked
    F8 xc = unpk(xpk[0]);
    F8 wu = unpk(*(const uint4*)&wcl[rb][lane*8]);
#pragma unroll
    for (int i = 0; i < RPW; ++i) {
      const uint4 xc_pk = xpk[i];
      const uint4 xd_pk = (i < RPW-1) ? xpk[i+1] : xdn;
      const F8 xd = unpk(xd_pk);
      const F8 wd = unpk(*(const uint4*)&wcl[rb + i + 1][lane*8]);
      const F8 w  = unpk(*(const uint4*)&wrl[rb + i][lane*8]);
      const F8 b  = unpk(*(const uint4*)&bl [rb + i][lane*8]);
      const uint_t ux  = (uint_t)__shfl_up((int)xc_pk.w, 1);
      const float xl0  = lane ? hi_h(ux) : 0.f;
      const uint_t dxp = (uint_t)__shfl_down((int)xc_pk.x, 1);
      const float xr7  = (lane < 63) ? lo_h(dxp) : 0.f;
      float o[8];
#pragma unroll
      for (int p = 0; p < 8; ++p) {
        const float wl  = p ? w.f[p-1] : wlmr[i];
        const float wrv = w.f[p];
        const float xl  = p ? xc.f[p-1] : xl0;
        const float xr  = (p < 7) ? xc.f[p+1] : xr7;
        const float kv  = 1.f + wu.f[p] + wd.f[p] + wl + wrv;
        const float av  = kv * xc.f[p] - wu.f[p]*xu.f[p] - wd.f[p]*xd.f[p]
                          - wl*xl - wrv*xr;
        o[p] = xc.f[p] + tau * (b.f[p] - av);
      }
      if (!last) {
        xpk[i] = pk8(o);
      } else {
        const int y = ys + rb + i;
        if (y >= y0 && y < y0 + STRIP && y < H) {
          if (stage == 0) {
            *(uint4*)(XWS + (size_t)j*S + (size_t)y*W + lane*8) = pk8(o);
          } else {
            float* dst = OUT + (size_t)j*S + (size_t)y*W + lane*8;
            *(float4*)dst       = make_float4(o[0],o[1],o[2],o[3]);
            *(float4*)(dst + 4) = make_float4(o[4],o[5],o[6],o[7]);
          }
        }
      }
      xu = xc; xc = xd; wu = wd;                // roll unpacked state down
    }
  }
}

extern "C" void kernel_launch(void* const* d_in, const int* in_sizes, int n_in,
                              void* d_out, int out_size, void* d_ws, size_t ws_size,
                              hipStream_t stream) {
  (void)in_sizes; (void)n_in; (void)out_size; (void)ws_size;
  const float* Bp = (const float*)d_in[0];
  const float* WC = (const float*)d_in[1];
  const float* WR = (const float*)d_in[2];
  ush* X5 = (ush*)d_ws;                         // 25.2 MB fp16 intermediate
  dim3 grid(NBX, NP), block(NTHR);
  cheb5<<<grid, block, 0, stream>>>(Bp, WC, WR, X5, nullptr, 0);
  cheb5<<<grid, block, 0, stream>>>(Bp, WC, WR, X5, (float*)d_out, 1);
}

// Round 8
// 246.105 us; speedup vs baseline: 2.5468x; 1.1570x over previous
//
#include <hip/hip_runtime.h>
#include <hip/hip_fp16.h>
#include <math.h>

#define H 512
#define W 512
#define S (H*W)
#define BS 16
#define CH 3
#define NP (BS*CH)

#define T5    5                        // steps per kernel (2 kernels = 10)
#define NW    8                        // waves per block
#define RPW   4                        // rows per wave (x in registers)
#define R     (NW*RPW)                 // 32 extended rows per block
#define STRIP (R - 2*T5)               // 22 rows correct after 5 steps
#define NBX   ((H + STRIP - 1)/STRIP)  // 24
#define NTHR  (NW*64)                  // 512

typedef unsigned int   uint_t;
typedef unsigned short ush;

struct F8 { float f[8]; };

__device__ __forceinline__ F8 unpk(uint4 r) {
  F8 o;
  float2 a = __half22float2(*(__half2*)&r.x); o.f[0]=a.x; o.f[1]=a.y;
  float2 b = __half22float2(*(__half2*)&r.y); o.f[2]=b.x; o.f[3]=b.y;
  float2 c = __half22float2(*(__half2*)&r.z); o.f[4]=c.x; o.f[5]=c.y;
  float2 d = __half22float2(*(__half2*)&r.w); o.f[6]=d.x; o.f[7]=d.y;
  return o;
}
__device__ __forceinline__ uint_t pk2(float a, float b) {
  __half2 h = __floats2half2_rn(a, b); return *(uint_t*)&h;
}
__device__ __forceinline__ uint4 pk8(const float* f) {
  return make_uint4(pk2(f[0],f[1]), pk2(f[2],f[3]), pk2(f[4],f[5]), pk2(f[6],f[7]));
}
__device__ __forceinline__ uint4 pkf8(float4 a, float4 b) {
  return make_uint4(pk2(a.x,a.y), pk2(a.z,a.w), pk2(b.x,b.y), pk2(b.z,b.w));
}
__device__ __forceinline__ float hi_h(uint_t u){ return __half22float2(*(__half2*)&u).y; }
__device__ __forceinline__ float lo_h(uint_t u){ return __half22float2(*(__half2*)&u).x; }

// tau = 1/(5 + 4 cos(pi(2k-1)/20)), Lebedev order k = 1,10,2,9,3,8,4,7,5,6
__device__ const float TAUS[10] = {
  0.11172248f, 0.95306479f, 0.11676753f, 0.69639146f, 0.12773959f,
  0.46049561f, 0.14671469f, 0.31406661f, 0.17775436f, 0.22860982f };

// 5 Chebyshev steps per kernel; two launches make the 10-step solve.
// ALL stencil data is register-resident across the t-loop: x packed fp16
// (16 VGPRs), wc packed (20), wr/K/b unpacked fp32 (96). K = 1+wu+wd+wl+wr
// precomputed once (saves 4 adds/px/step). The step loop touches LDS only
// for the boundary exchange (4 b128/step) + 2 shuffles/row.
// Occupancy/allocator contract (rounds 1/2/4/5/7): non-template kernel +
// __launch_bounds__(512,2) + LDS > 81 KiB -> 1 block/CU -> VGPR budget 256,
// granted as-needed. LDS = 97 KiB keeps us in that zone; ~190 regs peak
// fits with no spill (registers are FREE here up to 256 - LDS caps occupancy).
__global__ void __launch_bounds__(NTHR, 2)
cheb5(const float* __restrict__ Bsrc, const float* __restrict__ WCs,
      const float* __restrict__ WRs, ush* __restrict__ XWS,
      float* __restrict__ OUT, int stage)
{
  __shared__ __align__(16) ush wcl[R + 1][W];     // 33 KiB  wc rows ys-1..ys+31
  __shared__ __align__(16) ush wrl[R    ][W];     // 32 KiB  wr rows (col 511 = 0)
  __shared__ __align__(16) ush ex[2][NW][2][W];   // 32 KiB  boundary exchange

  const int j  = blockIdx.y;                    // plane 0..47
  const int bb = j / CH;                        // batch
  const int y0 = (int)blockIdx.x * STRIP;       // first interior row
  const int ys = y0 - T5;                       // first extended row
  const int tid = (int)threadIdx.x;
  const int wv = tid >> 6, lane = tid & 63;
  const uint4 zz = make_uint4(0,0,0,0);

  const float* bp = Bsrc + (size_t)j  * S;
  const float* wc = WCs  + (size_t)bb * (size_t)(H-1) * W;
  const float* wr = WRs  + (size_t)bb * (size_t)H * (W-1);
  const ush*   xp = XWS  + (size_t)j  * S;

  // ---- stage weights into LDS (fp32 -> packed fp16), cooperative ----
  for (int r = wv; r <= R; r += NW) {           // wc (R+1 rows)
    const int y = ys + r - 1;
    uint4 v = zz;
    if ((unsigned)y < (H-1)) {
      const float* p = wc + (size_t)y*W + lane*8;
      v = pkf8(*(const float4*)p, *(const float4*)(p + 4));
    }
    *(uint4*)&wcl[r][lane*8] = v;
  }
  for (int r = wv; r < R; r += NW) {            // wr (stride-511 src, pad col 511)
    const int y = ys + r;
    uint4 v = zz;
    if ((unsigned)y < H) {
      const float* q = wr + (size_t)y*(W-1) + lane*8;
      const float a0=q[0],a1=q[1],a2=q[2],a3=q[3],a4=q[4],a5=q[5],a6=q[6];
      const float a7 = (lane < 63) ? q[7] : 0.f;
      v = make_uint4(pk2(a0,a1), pk2(a2,a3), pk2(a4,a5), pk2(a6,a7));
    }
    *(uint4*)&wrl[r][lane*8] = v;
  }
  __syncthreads();

  // ---- hoist everything step-invariant into registers ----
  const int rb = wv * RPW;
  uint4 wcp[RPW + 1], xpk[RPW];
  float wf[RPW][8], kf[RPW][8], bf[RPW][8], wlmr[RPW];
#pragma unroll
  for (int q = 0; q <= RPW; ++q)
    wcp[q] = *(const uint4*)&wcl[rb + q][lane*8];
#pragma unroll
  for (int i = 0; i < RPW; ++i) {
    const int y = ys + rb + i;
    if ((unsigned)y < H) {                      // b stays fp32 (never rounded)
      const float* p = bp + (size_t)y*W + lane*8;
      const float4 b0 = *(const float4*)p, b1 = *(const float4*)(p + 4);
      bf[i][0]=b0.x; bf[i][1]=b0.y; bf[i][2]=b0.z; bf[i][3]=b0.w;
      bf[i][4]=b1.x; bf[i][5]=b1.y; bf[i][6]=b1.z; bf[i][7]=b1.w;
    } else {
#pragma unroll
      for (int p = 0; p < 8; ++p) bf[i][p] = 0.f;
    }
    const F8 w = unpk(*(const uint4*)&wrl[rb + i][lane*8]);
#pragma unroll
    for (int p = 0; p < 8; ++p) wf[i][p] = w.f[p];
    wlmr[i] = lane ? __half2float(*(const __half*)&wrl[rb + i][lane*8 - 1]) : 0.f;
    const F8 wu = unpk(wcp[i]), wd = unpk(wcp[i + 1]);
#pragma unroll
    for (int p = 0; p < 8; ++p) {               // diagonal K, fp32, once
      const float wl = p ? wf[i][p-1] : wlmr[i];
      kf[i][p] = 1.f + wu.f[p] + wd.f[p] + wl + wf[i][p];
    }
    if (stage == 0) {
      xpk[i] = pk8(bf[i]);                      // x0 = fp16(b)
    } else {
      xpk[i] = ((unsigned)y < H) ? *(const uint4*)(xp + (size_t)y*W + lane*8)
                                 : zz;          // x0 = stage-0 result
    }
  }

  // ---- 5 steps; one barrier per step; LDS = exchange only ----
#pragma unroll 1
  for (int t = 0; t < T5; ++t) {
    const float tau = TAUS[stage*T5 + t];
    const int buf = t & 1;
    *(uint4*)&ex[buf][wv][0][lane*8] = xpk[0];
    *(uint4*)&ex[buf][wv][1][lane*8] = xpk[RPW-1];
    __syncthreads();
    const uint4 xup = wv          ? *(const uint4*)&ex[buf][wv-1][1][lane*8] : zz;
    const uint4 xdn = (wv < NW-1) ? *(const uint4*)&ex[buf][wv+1][0][lane*8] : zz;
    const bool last = (t == T5-1);

    F8 xu = unpk(xup);                          // rolling up/center + wu
    F8 xc = unpk(xpk[0]);
    F8 wu = unpk(wcp[0]);
#pragma unroll
    for (int i = 0; i < RPW; ++i) {
      const uint4 xc_pk = xpk[i];
      const uint4 xd_pk = (i < RPW-1) ? xpk[i+1] : xdn;
      const F8 xd = unpk(xd_pk);
      const F8 wd = unpk(wcp[i + 1]);
      const uint_t ux  = (uint_t)__shfl_up((int)xc_pk.w, 1);
      const float xl0  = lane ? hi_h(ux) : 0.f;
      const uint_t dxp = (uint_t)__shfl_down((int)xc_pk.x, 1);
      const float xr7  = (lane < 63) ? lo_h(dxp) : 0.f;
      float o[8];
#pragma unroll
      for (int p = 0; p < 8; ++p) {
        const float wl  = p ? wf[i][p-1] : wlmr[i];
        const float xl  = p ? xc.f[p-1] : xl0;
        const float xr  = (p < 7) ? xc.f[p+1] : xr7;
        const float av  = kf[i][p]*xc.f[p] - wu.f[p]*xu.f[p] - wd.f[p]*xd.f[p]
                          - wl*xl - wf[i][p]*xr;
        o[p] = xc.f[p] + tau * (bf[i][p] - av);
      }
      if (!last) {
        xpk[i] = pk8(o);
      } else {
        const int y = ys + rb + i;
        if (y >= y0 && y < y0 + STRIP && y < H) {
          if (stage == 0) {
            *(uint4*)(XWS + (size_t)j*S + (size_t)y*W + lane*8) = pk8(o);
          } else {
            float* dst = OUT + (size_t)j*S + (size_t)y*W + lane*8;
            *(float4*)dst       = make_float4(o[0],o[1],o[2],o[3]);
            *(float4*)(dst + 4) = make_float4(o[4],o[5],o[6],o[7]);
          }
        }
      }
      xu = xc; xc = xd; wu = wd;                // roll down one row
    }
  }
}

extern "C" void kernel_launch(void* const* d_in, const int* in_sizes, int n_in,
                              void* d_out, int out_size, void* d_ws, size_t ws_size,
                              hipStream_t stream) {
  (void)in_sizes; (void)n_in; (void)out_size; (void)ws_size;
  const float* Bp = (const float*)d_in[0];
  const float* WC = (const float*)d_in[1];
  const float* WR = (const float*)d_in[2];
  ush* X5 = (ush*)d_ws;                         // 25.2 MB fp16 intermediate
  dim3 grid(NBX, NP), block(NTHR);
  cheb5<<<grid, block, 0, stream>>>(Bp, WC, WR, X5, nullptr, 0);
  cheb5<<<grid, block, 0, stream>>>(Bp, WC, WR, X5, (float*)d_out, 1);
}